// Round 9
// baseline (317.134 us; speedup 1.0000x reference)
//
#include <hip/hip_runtime.h>
#include <stdint.h>

typedef unsigned short u16;
typedef __bf16 bf16x8 __attribute__((ext_vector_type(8)));
typedef float f32x4 __attribute__((ext_vector_type(4)));
typedef unsigned short u16x8 __attribute__((ext_vector_type(8)));

__device__ __forceinline__ u16 f2bf(float f) {
  union { float f; uint32_t u; } x; x.f = f;
  uint32_t r = x.u + 0x7fffu + ((x.u >> 16) & 1u);   // RNE
  return (u16)(r >> 16);
}

// ---------- fused prologue: A fp32->bf16 and W q8_0->bf16 in one dispatch ----------
__global__ __launch_bounds__(256) void cvt_all(
    const float* __restrict__ A, u16* __restrict__ Ab, size_t n8a,
    const int* __restrict__ Wq, const float* __restrict__ S,
    u16* __restrict__ Wb, size_t n8w) {
  size_t i = (size_t)blockIdx.x * 256 + threadIdx.x;
  if (i < n8a) {
    const float4* p = (const float4*)(A + i * 8);
    float4 v0 = p[0], v1 = p[1];
    u16x8 r = { f2bf(v0.x), f2bf(v0.y), f2bf(v0.z), f2bf(v0.w),
                f2bf(v1.x), f2bf(v1.y), f2bf(v1.z), f2bf(v1.w) };
    *(u16x8*)(Ab + i * 8) = r;
  } else {
    size_t j = i - n8a;
    if (j >= n8w) return;
    const int4* p = (const int4*)(Wq + j * 8);
    int4 v0 = p[0], v1 = p[1];
    float s = S[j >> 2];  // 8 consecutive elems: 4 groups per 32-block
    u16x8 r = { f2bf((float)(v0.x - 128) * s), f2bf((float)(v0.y - 128) * s),
                f2bf((float)(v0.z - 128) * s), f2bf((float)(v0.w - 128) * s),
                f2bf((float)(v1.x - 128) * s), f2bf((float)(v1.y - 128) * s),
                f2bf((float)(v1.z - 128) * s), f2bf((float)(v1.w - 128) * s) };
    *(u16x8*)(Wb + j * 8) = r;
  }
}

__device__ __forceinline__ void load_lds_16B(const void* g, void* l) {
  __builtin_amdgcn_global_load_lds(
      (const __attribute__((address_space(1))) unsigned int*)g,
      (__attribute__((address_space(3))) unsigned int*)l, 16, 0, 0);
}

// ==== m201-faithful 8-phase 256x256 GEMM (R8, resubmitted after infra fail) ====
// C[M,N] = A[M,K] * W[N,K]^T, bf16 MFMA 16x16x32.
// 512 threads = 8 waves (2M x 4N), wave tile 128x64, BK=64, LDS 128KB dbuf.
// Phase skeleton ported EXACTLY from the verified m201 template:
//   { ds_read this phase's frags ; stage (2 gload_lds) ; s_barrier ;
//     s_waitcnt lgkmcnt(0) ; sched_barrier(0) ; setprio(1) ; 16 MFMA ;
//     setprio(0) ; s_barrier }
// Mechanism under test: reads issued PRE-barrier drain DURING barrier-arrival
// skew (fused latency), and the closing barrier keeps the 2 waves/SIMD's MFMA
// bursts aligned -> matrix pipe saturated. R3/R6/R7 varied barrier count and
// read distance; none used this coupling. Rule #18: lgkmcnt(0) asm must be
// followed by sched_barrier(0) or MFMAs hoist above the wait.
// Reads/tile: ph1 a0,b0 (12 b128) | ph2 a1 (8) | ph3 b1 (4) | ph4 none.
// Stage slots (same audited ledger as R7): ph1 B1(T+1)->NBUF, ph2 B0(T+2)->BUF,
// ph3 A0(T+2)->BUF, ph4 A1(T+2)->BUF + vmcnt(6): 14 outstanding -> drains
// oldest 8 = exactly tile T+1, leaves T+2's 6 (>=3 phases HBM flight).
// WAR safety (2-bar phases): all waves' phase-P reads complete before any wave
// passes P's CLOSING barrier -> stage at phase >= P+1 is safe; all slots >= +1.
// Register budget: 8-wave WG -> 256 regs/wave = 128 AGPR (acc) + 128 arch;
// addressing scalar-hoisted (readfirstlane wave, shared lane voffset, ds
// offsets folded into immediates) -> no spill (R3-R7: VGPR 120-128, WRITE=C).
#define BM 256
#define BN 256
#define BK 64

#define BAR()    __builtin_amdgcn_s_barrier()
#define VMBAR(N) asm volatile("s_waitcnt vmcnt(" #N ")\n\ts_barrier" ::: "memory")
#define LGKM0()  do { asm volatile("s_waitcnt lgkmcnt(0)" ::: "memory"); \
                      __builtin_amdgcn_sched_barrier(0); } while (0)

__global__ __launch_bounds__(512) void gemm8(
    const u16* __restrict__ Ab, const u16* __restrict__ Wb,
    float* __restrict__ C, int M, int N, int K) {
  __shared__ u16 As[2][BM * BK];   // 64 KB
  __shared__ u16 Bs[2][BN * BK];   // 64 KB

  const int NT = K >> 6;           // K-tiles of 64 (NT even, >= 4)
  const int K2 = K * 2;            // row stride in bytes
  const int tid = (int)threadIdx.x;
  const int lane = tid & 63;
  const int wvu = __builtin_amdgcn_readfirstlane(tid >> 6);  // wave idx, SGPR
  const int wm = wvu >> 2, wn = wvu & 3;        // 2 x 4 wave grid
  const int lrow = lane & 15, lq = lane >> 4;

  // T1: XCD-aware bijective swizzle (nwg = 256, % 8 == 0)
  const int nbx = N / BN;
  const int cpx = (int)gridDim.x >> 3;
  const int swz = ((int)blockIdx.x & 7) * cpx + ((int)blockIdx.x >> 3);
  const int m0 = (swz / nbx) * BM, n0 = (swz % nbx) * BN;

  // staging: lane l covers row base+(l>>3), k-chunk (l&7)^(l>>3) -> LDS slot
  // (l&7) holds chunk^(row&7): XOR swizzle with linear LDS dest (rule #21).
  const int srow = lane >> 3, schunk = (lane & 7) ^ srow;
  const uint32_t voff = (uint32_t)srow * (uint32_t)K2 + (uint32_t)schunk * 16;
  const char* baseA = (const char*)(Ab + (size_t)m0 * K);
  const char* baseB = (const char*)(Wb + (size_t)n0 * K);

  // ds_read element offsets: row = wq*span + subtile + lrow, slot = (ks*4+lq)^(row&7);
  // row&7 == lrow&7. Buffer + subtile folded into compile-time immediates.
  const int sx = lrow & 7;
  int offA[2], offB[2];
  #pragma unroll
  for (int ks = 0; ks < 2; ++ks) {
    const int slot = ((ks * 4 + lq) ^ sx) * 8;
    offA[ks] = (wm * 128 + lrow) * BK + slot;
    offB[ks] = (wn * 64 + lrow) * BK + slot;
  }

// quarter-groups: A-mh covers rows {mh*64+[0,64)} U {128+mh*64+[0,64)};
//                 B-nh covers rows {q*64+nh*32+[0,32) : q=0..3}. 2 loads/thread.
#define STAGE_A(BUF, MH, KT) do { \
    _Pragma("unroll") \
    for (int it = 0; it < 2; ++it) { \
      const int o = wvu * 2 + it; \
      const int rb = o * 8 + (o >> 3) * 64 + (MH) * 64; \
      load_lds_16B(baseA + (size_t)rb * K2 + (size_t)(KT) * 128 + voff, \
                   (char*)&As[BUF][0] + rb * 128); \
    } } while (0)

#define STAGE_B(BUF, NH, KT) do { \
    _Pragma("unroll") \
    for (int it = 0; it < 2; ++it) { \
      const int o = wvu * 2 + it; \
      const int rb = (o >> 2) * 64 + (o & 3) * 8 + (NH) * 32; \
      load_lds_16B(baseB + (size_t)rb * K2 + (size_t)(KT) * 128 + voff, \
                   (char*)&Bs[BUF][0] + rb * 128); \
    } } while (0)

#define LDA(DST, BUF, MH) do { \
    _Pragma("unroll") \
    for (int ii = 0; ii < 4; ++ii) \
      _Pragma("unroll") \
      for (int ks = 0; ks < 2; ++ks) \
        DST[ii][ks] = *(const bf16x8*)((const u16*)As + \
            ((BUF) * (BM * BK) + ((MH) * 64 + ii * 16) * BK) + offA[ks]); \
  } while (0)

#define LDB(DST, BUF, NH) do { \
    _Pragma("unroll") \
    for (int jj = 0; jj < 2; ++jj) \
      _Pragma("unroll") \
      for (int ks = 0; ks < 2; ++ks) \
        DST[jj][ks] = *(const bf16x8*)((const u16*)Bs + \
            ((BUF) * (BN * BK) + ((NH) * 32 + jj * 16) * BK) + offB[ks]); \
  } while (0)

#define QUAD(MH, NH, ASET, BSET) do { \
    __builtin_amdgcn_s_setprio(1); \
    _Pragma("unroll") \
    for (int ii = 0; ii < 4; ++ii) \
      _Pragma("unroll") \
      for (int jj = 0; jj < 2; ++jj) { \
        acc[(MH)*4+ii][(NH)*2+jj] = __builtin_amdgcn_mfma_f32_16x16x32_bf16( \
            ASET[ii][0], BSET[jj][0], acc[(MH)*4+ii][(NH)*2+jj], 0, 0, 0); \
        acc[(MH)*4+ii][(NH)*2+jj] = __builtin_amdgcn_mfma_f32_16x16x32_bf16( \
            ASET[ii][1], BSET[jj][1], acc[(MH)*4+ii][(NH)*2+jj], 0, 0, 0); \
      } \
    __builtin_amdgcn_s_setprio(0); \
  } while (0)

  f32x4 acc[8][4] = {};
  bf16x8 a0[4][2], a1[4][2], b0[2][2], b1[2][2];

  // prologue: tile0 -> buf0 (8 loads), tile1 -> buf1 {B0,A0,A1} (6 loads;
  // B1(1) is staged at ph1 of tile 0, matching the steady-state slot)
  STAGE_B(0, 0, 0); STAGE_A(0, 0, 0); STAGE_A(0, 1, 0); STAGE_B(0, 1, 0);
  STAGE_B(1, 0, 1); STAGE_A(1, 0, 1); STAGE_A(1, 1, 1);
  VMBAR(6);                      // tile0's 8 landed; tile1's 6 stay in flight

#define HALF(T, BUF, NBUF) do { \
    /* ph1 */ \
    LDA(a0, BUF, 0); LDB(b0, BUF, 0); \
    STAGE_B(NBUF, 1, (T) + 1); \
    BAR(); \
    LGKM0(); \
    QUAD(0, 0, a0, b0); \
    BAR(); \
    /* ph2 */ \
    LDA(a1, BUF, 1); \
    STAGE_B(BUF, 0, (T) + 2); \
    BAR(); \
    LGKM0(); \
    QUAD(1, 0, a1, b0); \
    BAR(); \
    /* ph3 */ \
    LDB(b1, BUF, 1); \
    STAGE_A(BUF, 0, (T) + 2); \
    BAR(); \
    LGKM0(); \
    QUAD(0, 1, a0, b1); \
    BAR(); \
    /* ph4 */ \
    STAGE_A(BUF, 1, (T) + 2); \
    VMBAR(6); \
    QUAD(1, 1, a1, b1); \
    BAR(); \
  } while (0)

  // tail tile NT-2: stages only B1(NT-1); full vmcnt drain at ph4
#define HALF_T1(T, BUF, NBUF) do { \
    LDA(a0, BUF, 0); LDB(b0, BUF, 0); \
    STAGE_B(NBUF, 1, (T) + 1); \
    BAR(); \
    LGKM0(); \
    QUAD(0, 0, a0, b0); \
    BAR(); \
    LDA(a1, BUF, 1); \
    BAR(); \
    LGKM0(); \
    QUAD(1, 0, a1, b0); \
    BAR(); \
    LDB(b1, BUF, 1); \
    BAR(); \
    LGKM0(); \
    QUAD(0, 1, a0, b1); \
    BAR(); \
    VMBAR(0); \
    QUAD(1, 1, a1, b1); \
    BAR(); \
  } while (0)

  // last tile: reads only (buf certified by T1's vmcnt(0)+barrier)
#define HALF_T2(BUF) do { \
    LDA(a0, BUF, 0); LDB(b0, BUF, 0); \
    BAR(); \
    LGKM0(); \
    QUAD(0, 0, a0, b0); \
    BAR(); \
    LDA(a1, BUF, 1); \
    BAR(); \
    LGKM0(); \
    QUAD(1, 0, a1, b0); \
    BAR(); \
    LDB(b1, BUF, 1); \
    BAR(); \
    LGKM0(); \
    QUAD(0, 1, a0, b1); \
    QUAD(1, 1, a1, b1); \
  } while (0)

  int t = 0;
  for (; t + 3 < NT; t += 2) {   // branchless steady state
    HALF(t, 0, 1);
    HALF(t + 1, 1, 0);
  }
  // t == NT-2 (NT even)
  HALF_T1(t, 0, 1);
  HALF_T2(1);

  // epilogue: C/D layout col=lane&15 (n), row=(lane>>4)*4+reg (m)
  #pragma unroll
  for (int i = 0; i < 8; ++i)
    #pragma unroll
    for (int r = 0; r < 4; ++r) {
      const int gm = m0 + wm * 128 + i * 16 + lq * 4 + r;
      float* crow = C + (size_t)gm * N + n0 + wn * 64 + lrow;
      #pragma unroll
      for (int j = 0; j < 4; ++j) crow[j * 16] = acc[i][j][r];
    }

#undef HALF_T2
#undef HALF_T1
#undef HALF
#undef QUAD
#undef LDB
#undef LDA
#undef STAGE_B
#undef STAGE_A
}

// ================= fallback GEMM for small-workspace paths =================
// (harness-verified 256x128 tile, BK=32; MODE 1: A fused from fp32, W bf16
// from ws; MODE 2: both fused, no ws)
#define FBM 256
#define FBN 128
#define FBK 32

template <int MODE>
__global__ __launch_bounds__(256, 2) void gemm_fb(
    const u16* __restrict__ Ab, const u16* __restrict__ Wb,
    const float* __restrict__ Af, const int* __restrict__ Wq,
    const float* __restrict__ Sc, float* __restrict__ C,
    int M, int N, int K) {
  __shared__ u16 As[FBM * FBK];  // 16 KB
  __shared__ u16 Bs[FBN * FBK];  //  8 KB

  const int tid = threadIdx.x;
  const int wave = tid >> 6, lane = tid & 63;
  const int m0 = blockIdx.y * FBM, n0 = blockIdx.x * FBN;
  const int wm = (wave & 1) * 128, wn = (wave >> 1) * 64;
  const int lrow = lane & 15, lq = lane >> 4;

  const u16* gB[2]; u16* dB[2];
  if constexpr (MODE <= 1) {
    #pragma unroll
    for (int it = 0; it < 2; ++it) {        // B: 512 chunks, 2/wave-lane
      int q = wave * 128 + it * 64 + lane;
      int row = q >> 2, s = q & 3;
      int c = (s - (row >> 1)) & 3;
      gB[it] = Wb + (size_t)(n0 + row) * K + c * 8;
      dB[it] = Bs + (size_t)(wave * 128 + it * 64) * 8;
    }
  }

  const u16* fA[8]; const u16* fB[4];
  #pragma unroll
  for (int i = 0; i < 8; ++i) {
    int row = wm + i * 16 + lrow;
    int s = (lq + (row >> 1)) & 3;
    fA[i] = As + row * FBK + s * 8;
  }
  #pragma unroll
  for (int j = 0; j < 4; ++j) {
    int row = wn + j * 16 + lrow;
    int s = (lq + (row >> 1)) & 3;
    fB[j] = Bs + row * FBK + s * 8;
  }

  f32x4 acc[8][4] = {};

  for (int k0 = 0; k0 < K; k0 += FBK) {
    #pragma unroll
    for (int it = 0; it < 4; ++it) {
      int g = it * 256 + tid;
      int row = g >> 2, c8 = g & 3;
      int s = (c8 + (row >> 1)) & 3;
      const float4* p = (const float4*)(Af + (size_t)(m0 + row) * K + k0 + c8 * 8);
      float4 v0 = p[0], v1 = p[1];
      u16x8 r = { f2bf(v0.x), f2bf(v0.y), f2bf(v0.z), f2bf(v0.w),
                  f2bf(v1.x), f2bf(v1.y), f2bf(v1.z), f2bf(v1.w) };
      *(u16x8*)(As + row * FBK + s * 8) = r;
    }
    if constexpr (MODE == 1) {
      #pragma unroll
      for (int it = 0; it < 2; ++it) load_lds_16B(gB[it] + k0, dB[it]);
    } else {
      #pragma unroll
      for (int it = 0; it < 2; ++it) {    // fused W: 512 chunks
        int g = it * 256 + tid;
        int row = g >> 2, c8 = g & 3;
        int s = (c8 + (row >> 1)) & 3;
        const int4* p = (const int4*)(Wq + (size_t)(n0 + row) * K + k0 + c8 * 8);
        int4 v0 = p[0], v1 = p[1];
        float sc = Sc[(size_t)(n0 + row) * (K >> 5) + (k0 >> 5)];
        u16x8 r = { f2bf((float)(v0.x - 128) * sc), f2bf((float)(v0.y - 128) * sc),
                    f2bf((float)(v0.z - 128) * sc), f2bf((float)(v0.w - 128) * sc),
                    f2bf((float)(v1.x - 128) * sc), f2bf((float)(v1.y - 128) * sc),
                    f2bf((float)(v1.z - 128) * sc), f2bf((float)(v1.w - 128) * sc) };
        *(u16x8*)(Bs + row * FBK + s * 8) = r;
      }
    }
    __syncthreads();

    bf16x8 a[8], b[4];
    #pragma unroll
    for (int i = 0; i < 8; ++i) a[i] = *(const bf16x8*)fA[i];
    #pragma unroll
    for (int j = 0; j < 4; ++j) b[j] = *(const bf16x8*)fB[j];
    #pragma unroll
    for (int i = 0; i < 8; ++i)
      #pragma unroll
      for (int j = 0; j < 4; ++j)
        acc[i][j] = __builtin_amdgcn_mfma_f32_16x16x32_bf16(a[i], b[j], acc[i][j], 0, 0, 0);
    __syncthreads();
  }

  #pragma unroll
  for (int i = 0; i < 8; ++i) {
    #pragma unroll
    for (int r = 0; r < 4; ++r) {
      int gm = m0 + wm + i * 16 + lq * 4 + r;
      float* crow = C + (size_t)gm * N + n0 + wn + lrow;
      #pragma unroll
      for (int j = 0; j < 4; ++j) crow[j * 16] = acc[i][j][r];
    }
  }
}

extern "C" void kernel_launch(void* const* d_in, const int* in_sizes, int n_in,
                              void* d_out, int out_size, void* d_ws, size_t ws_size,
                              hipStream_t stream) {
  const float* A  = (const float*)d_in[0];
  const int*   Wq = (const int*)d_in[1];
  const float* S  = (const float*)d_in[2];
  float* C = (float*)d_out;

  const int K = 4096;                 // I (infeatures)
  const int N = in_sizes[1] / K;      // O = 4096
  const int M = in_sizes[0] / K;      // B*S = 4096

  const size_t needA = (size_t)M * K * sizeof(u16);   // 32 MB
  const size_t needW = (size_t)N * K * sizeof(u16);   // 32 MB

  if (ws_size >= needA + needW) {
    u16* Ab = (u16*)d_ws;
    u16* Wb = (u16*)((char*)d_ws + needA);
    size_t nA8 = (size_t)M * K / 8, nW8 = (size_t)N * K / 8;
    cvt_all<<<(int)((nA8 + nW8 + 255) / 256), 256, 0, stream>>>(A, Ab, nA8, Wq, S, Wb, nW8);
    gemm8<<<dim3((M / BM) * (N / BN)), dim3(512), 0, stream>>>(Ab, Wb, C, M, N, K);
  } else if (ws_size >= needW) {
    u16* Wb = (u16*)d_ws;
    size_t nW8 = (size_t)N * K / 8;
    cvt_all<<<(int)((nW8 + 255) / 256), 256, 0, stream>>>(nullptr, nullptr, 0, Wq, S, Wb, nW8);
    gemm_fb<1><<<dim3(N / FBN, M / FBM), dim3(256), 0, stream>>>(nullptr, Wb, A, nullptr, nullptr, C, M, N, K);
  } else {
    gemm_fb<2><<<dim3(N / FBN, M / FBM), dim3(256), 0, stream>>>(nullptr, nullptr, A, Wq, S, C, M, N, K);
  }
}

// Round 11
// 274.421 us; speedup vs baseline: 1.1556x; 1.1556x over previous
//
#include <hip/hip_runtime.h>
#include <stdint.h>

typedef unsigned short u16;
typedef __bf16 bf16x8 __attribute__((ext_vector_type(8)));
typedef float f32x4 __attribute__((ext_vector_type(4)));
typedef unsigned short u16x8 __attribute__((ext_vector_type(8)));

__device__ __forceinline__ u16 f2bf(float f) {
  union { float f; uint32_t u; } x; x.f = f;
  uint32_t r = x.u + 0x7fffu + ((x.u >> 16) & 1u);   // RNE
  return (u16)(r >> 16);
}

// ---------- fused prologue: A fp32->bf16 and W q8_0->bf16 in one dispatch ----------
__global__ __launch_bounds__(256) void cvt_all(
    const float* __restrict__ A, u16* __restrict__ Ab, size_t n8a,
    const int* __restrict__ Wq, const float* __restrict__ S,
    u16* __restrict__ Wb, size_t n8w) {
  size_t i = (size_t)blockIdx.x * 256 + threadIdx.x;
  if (i < n8a) {
    const float4* p = (const float4*)(A + i * 8);
    float4 v0 = p[0], v1 = p[1];
    u16x8 r = { f2bf(v0.x), f2bf(v0.y), f2bf(v0.z), f2bf(v0.w),
                f2bf(v1.x), f2bf(v1.y), f2bf(v1.z), f2bf(v1.w) };
    *(u16x8*)(Ab + i * 8) = r;
  } else {
    size_t j = i - n8a;
    if (j >= n8w) return;
    const int4* p = (const int4*)(Wq + j * 8);
    int4 v0 = p[0], v1 = p[1];
    float s = S[j >> 2];  // 8 consecutive elems: 4 groups per 32-block
    u16x8 r = { f2bf((float)(v0.x - 128) * s), f2bf((float)(v0.y - 128) * s),
                f2bf((float)(v0.z - 128) * s), f2bf((float)(v0.w - 128) * s),
                f2bf((float)(v1.x - 128) * s), f2bf((float)(v1.y - 128) * s),
                f2bf((float)(v1.z - 128) * s), f2bf((float)(v1.w - 128) * s) };
    *(u16x8*)(Wb + j * 8) = r;
  }
}

__device__ __forceinline__ void load_lds_16B(const void* g, void* l) {
  __builtin_amdgcn_global_load_lds(
      (const __attribute__((address_space(1))) unsigned int*)g,
      (__attribute__((address_space(3))) unsigned int*)l, 16, 0, 0);
}

// ==== 4-barrier 256x256 GEMM, deep read-ahead (R10, resubmit after infra fail) ====
// C[M,N] = A[M,K] * W[N,K]^T, bf16 MFMA 16x16x32.
// 512 threads = 8 waves (2M x 4N), wave tile 128x64, BK=64, LDS 128KB dbuf.
// ROOFLINE REFRAME: per tile per CU, fragment reads = 192 x ds_read_b128
// (196KB) + 64KB gload_lds writes ~= 3050 cyc at 85 B/cyc LDS throughput >
// 2066 cyc MFMA floor -> the kernel is LDS-BANDWIDTH-bound (~82us floor).
// R7 (122us) = 67% LDS util; the gap is LDS pipe idle from bursty issue
// (12/8/4/0 reads per phase). R10: after ph4's VMBAR(6), ALL 24 reads of
// tile T+1 are certified (drain ledger includes B1(T+1)) -> issue a0,b0
// before QUAD(1,1) and a1,b1 AFTER it (post-last-use: same registers, no
// renaming, no VGPR growth). Phases 1-3 carry zero read-issue; the LDS pipe
// gets one continuous 24-deep queue spanning the vmcnt drain + 3 MFMA
// clusters. Counted lgkm waits (<=12, fits 4-bit field); 4 barriers/tile.
// WAR ledger (read-complete vs region-rewrite, all >=1 closing barrier):
//  a0/b0: done @T+1 ph1 QUAD lgkm; B0 region rewritten @T+1 ph2 stage. OK
//  a1: done @T+1 ph2; A1 region rewritten @T+1 ph4. OK
//  b1: done @T+1 ph3; B1 region rewritten @T+2 ph1. OK
// vmcnt ledger @ph4 VMBAR(6): 14 outstanding (T+1's 8 + T+2's 6) -> drains
// oldest 8 = tile T+1 complete. Tail: T1 drains vmcnt(0) then pre-reads all
// of NT-1; T2 is pure QUADs (no barriers needed - no LDS writes remain).
// Register budget: 8-wave WG -> 256 regs/wave = 128 AGPR (acc) + 128 arch;
// addressing scalar-hoisted -> no spill (R3-R9: VGPR 120-128, WRITE=C only).
#define BM 256
#define BN 256
#define BK 64

#define BAR()    __builtin_amdgcn_s_barrier()
#define VMBAR(N) asm volatile("s_waitcnt vmcnt(" #N ")\n\ts_barrier" ::: "memory")

__global__ __launch_bounds__(512) void gemm8(
    const u16* __restrict__ Ab, const u16* __restrict__ Wb,
    float* __restrict__ C, int M, int N, int K) {
  __shared__ u16 As[2][BM * BK];   // 64 KB
  __shared__ u16 Bs[2][BN * BK];   // 64 KB

  const int NT = K >> 6;           // K-tiles of 64 (NT even, >= 4)
  const int K2 = K * 2;            // row stride in bytes
  const int tid = (int)threadIdx.x;
  const int lane = tid & 63;
  const int wvu = __builtin_amdgcn_readfirstlane(tid >> 6);  // wave idx, SGPR
  const int wm = wvu >> 2, wn = wvu & 3;        // 2 x 4 wave grid
  const int lrow = lane & 15, lq = lane >> 4;

  // T1: XCD-aware bijective swizzle (nwg = 256, % 8 == 0)
  const int nbx = N / BN;
  const int cpx = (int)gridDim.x >> 3;
  const int swz = ((int)blockIdx.x & 7) * cpx + ((int)blockIdx.x >> 3);
  const int m0 = (swz / nbx) * BM, n0 = (swz % nbx) * BN;

  // staging: lane l covers row base+(l>>3), k-chunk (l&7)^(l>>3) -> LDS slot
  // (l&7) holds chunk^(row&7): XOR swizzle with linear LDS dest (rule #21).
  const int srow = lane >> 3, schunk = (lane & 7) ^ srow;
  const uint32_t voff = (uint32_t)srow * (uint32_t)K2 + (uint32_t)schunk * 16;
  const char* baseA = (const char*)(Ab + (size_t)m0 * K);
  const char* baseB = (const char*)(Wb + (size_t)n0 * K);

  // ds_read element offsets: row = wq*span + subtile + lrow, slot = (ks*4+lq)^(row&7);
  // row&7 == lrow&7. Buffer + subtile folded into compile-time immediates.
  const int sx = lrow & 7;
  int offA[2], offB[2];
  #pragma unroll
  for (int ks = 0; ks < 2; ++ks) {
    const int slot = ((ks * 4 + lq) ^ sx) * 8;
    offA[ks] = (wm * 128 + lrow) * BK + slot;
    offB[ks] = (wn * 64 + lrow) * BK + slot;
  }

// quarter-groups: A-mh covers rows {mh*64+[0,64)} U {128+mh*64+[0,64)};
//                 B-nh covers rows {q*64+nh*32+[0,32) : q=0..3}. 2 loads/thread.
#define STAGE_A(BUF, MH, KT) do { \
    _Pragma("unroll") \
    for (int it = 0; it < 2; ++it) { \
      const int o = wvu * 2 + it; \
      const int rb = o * 8 + (o >> 3) * 64 + (MH) * 64; \
      load_lds_16B(baseA + (size_t)rb * K2 + (size_t)(KT) * 128 + voff, \
                   (char*)&As[BUF][0] + rb * 128); \
    } } while (0)

#define STAGE_B(BUF, NH, KT) do { \
    _Pragma("unroll") \
    for (int it = 0; it < 2; ++it) { \
      const int o = wvu * 2 + it; \
      const int rb = (o >> 2) * 64 + (o & 3) * 8 + (NH) * 32; \
      load_lds_16B(baseB + (size_t)rb * K2 + (size_t)(KT) * 128 + voff, \
                   (char*)&Bs[BUF][0] + rb * 128); \
    } } while (0)

#define LDA(DST, BUF, MH) do { \
    _Pragma("unroll") \
    for (int ii = 0; ii < 4; ++ii) \
      _Pragma("unroll") \
      for (int ks = 0; ks < 2; ++ks) \
        DST[ii][ks] = *(const bf16x8*)((const u16*)As + \
            ((BUF) * (BM * BK) + ((MH) * 64 + ii * 16) * BK) + offA[ks]); \
  } while (0)

#define LDB(DST, BUF, NH) do { \
    _Pragma("unroll") \
    for (int jj = 0; jj < 2; ++jj) \
      _Pragma("unroll") \
      for (int ks = 0; ks < 2; ++ks) \
        DST[jj][ks] = *(const bf16x8*)((const u16*)Bs + \
            ((BUF) * (BN * BK) + ((NH) * 32 + jj * 16) * BK) + offB[ks]); \
  } while (0)

#define QUAD(MH, NH, ASET, BSET) do { \
    __builtin_amdgcn_s_setprio(1); \
    _Pragma("unroll") \
    for (int ii = 0; ii < 4; ++ii) \
      _Pragma("unroll") \
      for (int jj = 0; jj < 2; ++jj) { \
        acc[(MH)*4+ii][(NH)*2+jj] = __builtin_amdgcn_mfma_f32_16x16x32_bf16( \
            ASET[ii][0], BSET[jj][0], acc[(MH)*4+ii][(NH)*2+jj], 0, 0, 0); \
        acc[(MH)*4+ii][(NH)*2+jj] = __builtin_amdgcn_mfma_f32_16x16x32_bf16( \
            ASET[ii][1], BSET[jj][1], acc[(MH)*4+ii][(NH)*2+jj], 0, 0, 0); \
      } \
    __builtin_amdgcn_s_setprio(0); \
  } while (0)

  f32x4 acc[8][4] = {};
  bf16x8 a0[4][2], a1[4][2], b0[2][2], b1[2][2];

  // prologue: tile0 -> buf0 (8 loads), tile1 -> buf1 {B0,A0,A1} (6 loads;
  // B1(1) is staged at ph1 of tile 0, matching the steady-state slot).
  // After VMBAR: pre-read ALL of tile0's fragments (the ph4 read slot).
  STAGE_B(0, 0, 0); STAGE_A(0, 0, 0); STAGE_A(0, 1, 0); STAGE_B(0, 1, 0);
  STAGE_B(1, 0, 1); STAGE_A(1, 0, 1); STAGE_A(1, 1, 1);
  VMBAR(6);                      // tile0's 8 landed; tile1's 6 stay in flight
  LDA(a0, 0, 0); LDB(b0, 0, 0);
  LDA(a1, 0, 1); LDB(b1, 0, 1);

  // Per K-tile T (buffer BUF = T&1):
  //  ph1: stage B1(T+1)->NBUF | BAR | Q(0,0)
  //  ph2: stage B0(T+2)->BUF  | BAR | Q(1,0)
  //  ph3: stage A0(T+2)->BUF  | BAR | Q(0,1)
  //  ph4: stage A1(T+2)->BUF | vmcnt(6)+BAR | read a0,b0(T+1) | Q(1,1)
  //       | read a1,b1(T+1)   <- post-last-use: same regs, deep LDS queue
#define HALF(T, BUF, NBUF) do { \
    /* ph1 */ \
    STAGE_B(NBUF, 1, (T) + 1); \
    BAR(); \
    QUAD(0, 0, a0, b0); \
    /* ph2 */ \
    STAGE_B(BUF, 0, (T) + 2); \
    BAR(); \
    QUAD(1, 0, a1, b0); \
    /* ph3 */ \
    STAGE_A(BUF, 0, (T) + 2); \
    BAR(); \
    QUAD(0, 1, a0, b1); \
    /* ph4 */ \
    STAGE_A(BUF, 1, (T) + 2); \
    VMBAR(6); \
    LDA(a0, NBUF, 0); LDB(b0, NBUF, 0); \
    QUAD(1, 1, a1, b1); \
    LDA(a1, NBUF, 1); LDB(b1, NBUF, 1); \
  } while (0)

  // tail tile NT-2: stages only B1(NT-1); full vmcnt drain; pre-read NT-1
#define HALF_T1(T, BUF, NBUF) do { \
    STAGE_B(NBUF, 1, (T) + 1); \
    BAR(); \
    QUAD(0, 0, a0, b0); \
    BAR(); \
    QUAD(1, 0, a1, b0); \
    BAR(); \
    QUAD(0, 1, a0, b1); \
    VMBAR(0); \
    LDA(a0, NBUF, 0); LDB(b0, NBUF, 0); \
    QUAD(1, 1, a1, b1); \
    LDA(a1, NBUF, 1); LDB(b1, NBUF, 1); \
  } while (0)

  // last tile: pure QUADs (all reads pre-issued; no LDS writes remain, so
  // no barriers needed; compiler inserts counted lgkm waits)
#define HALF_T2() do { \
    QUAD(0, 0, a0, b0); \
    QUAD(1, 0, a1, b0); \
    QUAD(0, 1, a0, b1); \
    QUAD(1, 1, a1, b1); \
  } while (0)

  int t = 0;
  for (; t + 3 < NT; t += 2) {   // branchless steady state
    HALF(t, 0, 1);
    HALF(t + 1, 1, 0);
  }
  // t == NT-2 (NT even)
  HALF_T1(t, 0, 1);
  HALF_T2();

  // epilogue: C/D layout col=lane&15 (n), row=(lane>>4)*4+reg (m)
  #pragma unroll
  for (int i = 0; i < 8; ++i)
    #pragma unroll
    for (int r = 0; r < 4; ++r) {
      const int gm = m0 + wm * 128 + i * 16 + lq * 4 + r;
      float* crow = C + (size_t)gm * N + n0 + wn * 64 + lrow;
      #pragma unroll
      for (int j = 0; j < 4; ++j) crow[j * 16] = acc[i][j][r];
    }

#undef HALF_T2
#undef HALF_T1
#undef HALF
#undef QUAD
#undef LDB
#undef LDA
#undef STAGE_B
#undef STAGE_A
}

// ================= fallback GEMM for small-workspace paths =================
// (harness-verified 256x128 tile, BK=32; MODE 1: A fused from fp32, W bf16
// from ws; MODE 2: both fused, no ws)
#define FBM 256
#define FBN 128
#define FBK 32

template <int MODE>
__global__ __launch_bounds__(256, 2) void gemm_fb(
    const u16* __restrict__ Ab, const u16* __restrict__ Wb,
    const float* __restrict__ Af, const int* __restrict__ Wq,
    const float* __restrict__ Sc, float* __restrict__ C,
    int M, int N, int K) {
  __shared__ u16 As[FBM * FBK];  // 16 KB
  __shared__ u16 Bs[FBN * FBK];  //  8 KB

  const int tid = threadIdx.x;
  const int wave = tid >> 6, lane = tid & 63;
  const int m0 = blockIdx.y * FBM, n0 = blockIdx.x * FBN;
  const int wm = (wave & 1) * 128, wn = (wave >> 1) * 64;
  const int lrow = lane & 15, lq = lane >> 4;

  const u16* gB[2]; u16* dB[2];
  if constexpr (MODE <= 1) {
    #pragma unroll
    for (int it = 0; it < 2; ++it) {        // B: 512 chunks, 2/wave-lane
      int q = wave * 128 + it * 64 + lane;
      int row = q >> 2, s = q & 3;
      int c = (s - (row >> 1)) & 3;
      gB[it] = Wb + (size_t)(n0 + row) * K + c * 8;
      dB[it] = Bs + (size_t)(wave * 128 + it * 64) * 8;
    }
  }

  const u16* fA[8]; const u16* fB[4];
  #pragma unroll
  for (int i = 0; i < 8; ++i) {
    int row = wm + i * 16 + lrow;
    int s = (lq + (row >> 1)) & 3;
    fA[i] = As + row * FBK + s * 8;
  }
  #pragma unroll
  for (int j = 0; j < 4; ++j) {
    int row = wn + j * 16 + lrow;
    int s = (lq + (row >> 1)) & 3;
    fB[j] = Bs + row * FBK + s * 8;
  }

  f32x4 acc[8][4] = {};

  for (int k0 = 0; k0 < K; k0 += FBK) {
    #pragma unroll
    for (int it = 0; it < 4; ++it) {
      int g = it * 256 + tid;
      int row = g >> 2, c8 = g & 3;
      int s = (c8 + (row >> 1)) & 3;
      const float4* p = (const float4*)(Af + (size_t)(m0 + row) * K + k0 + c8 * 8);
      float4 v0 = p[0], v1 = p[1];
      u16x8 r = { f2bf(v0.x), f2bf(v0.y), f2bf(v0.z), f2bf(v0.w),
                  f2bf(v1.x), f2bf(v1.y), f2bf(v1.z), f2bf(v1.w) };
      *(u16x8*)(As + row * FBK + s * 8) = r;
    }
    if constexpr (MODE == 1) {
      #pragma unroll
      for (int it = 0; it < 2; ++it) load_lds_16B(gB[it] + k0, dB[it]);
    } else {
      #pragma unroll
      for (int it = 0; it < 2; ++it) {    // fused W: 512 chunks
        int g = it * 256 + tid;
        int row = g >> 2, c8 = g & 3;
        int s = (c8 + (row >> 1)) & 3;
        const int4* p = (const int4*)(Wq + (size_t)(n0 + row) * K + k0 + c8 * 8);
        int4 v0 = p[0], v1 = p[1];
        float sc = Sc[(size_t)(n0 + row) * (K >> 5) + (k0 >> 5)];
        u16x8 r = { f2bf((float)(v0.x - 128) * sc), f2bf((float)(v0.y - 128) * sc),
                    f2bf((float)(v0.z - 128) * sc), f2bf((float)(v0.w - 128) * sc),
                    f2bf((float)(v1.x - 128) * sc), f2bf((float)(v1.y - 128) * sc),
                    f2bf((float)(v1.z - 128) * sc), f2bf((float)(v1.w - 128) * sc) };
        *(u16x8*)(Bs + row * FBK + s * 8) = r;
      }
    }
    __syncthreads();

    bf16x8 a[8], b[4];
    #pragma unroll
    for (int i = 0; i < 8; ++i) a[i] = *(const bf16x8*)fA[i];
    #pragma unroll
    for (int j = 0; j < 4; ++j) b[j] = *(const bf16x8*)fB[j];
    #pragma unroll
    for (int i = 0; i < 8; ++i)
      #pragma unroll
      for (int j = 0; j < 4; ++j)
        acc[i][j] = __builtin_amdgcn_mfma_f32_16x16x32_bf16(a[i], b[j], acc[i][j], 0, 0, 0);
    __syncthreads();
  }

  #pragma unroll
  for (int i = 0; i < 8; ++i) {
    #pragma unroll
    for (int r = 0; r < 4; ++r) {
      int gm = m0 + wm + i * 16 + lq * 4 + r;
      float* crow = C + (size_t)gm * N + n0 + wn + lrow;
      #pragma unroll
      for (int j = 0; j < 4; ++j) crow[j * 16] = acc[i][j][r];
    }
  }
}

extern "C" void kernel_launch(void* const* d_in, const int* in_sizes, int n_in,
                              void* d_out, int out_size, void* d_ws, size_t ws_size,
                              hipStream_t stream) {
  const float* A  = (const float*)d_in[0];
  const int*   Wq = (const int*)d_in[1];
  const float* S  = (const float*)d_in[2];
  float* C = (float*)d_out;

  const int K = 4096;                 // I (infeatures)
  const int N = in_sizes[1] / K;      // O = 4096
  const int M = in_sizes[0] / K;      // B*S = 4096

  const size_t needA = (size_t)M * K * sizeof(u16);   // 32 MB
  const size_t needW = (size_t)N * K * sizeof(u16);   // 32 MB

  if (ws_size >= needA + needW) {
    u16* Ab = (u16*)d_ws;
    u16* Wb = (u16*)((char*)d_ws + needA);
    size_t nA8 = (size_t)M * K / 8, nW8 = (size_t)N * K / 8;
    cvt_all<<<(int)((nA8 + nW8 + 255) / 256), 256, 0, stream>>>(A, Ab, nA8, Wq, S, Wb, nW8);
    gemm8<<<dim3((M / BM) * (N / BN)), dim3(512), 0, stream>>>(Ab, Wb, C, M, N, K);
  } else if (ws_size >= needW) {
    u16* Wb = (u16*)d_ws;
    size_t nW8 = (size_t)N * K / 8;
    cvt_all<<<(int)((nW8 + 255) / 256), 256, 0, stream>>>(nullptr, nullptr, 0, Wq, S, Wb, nW8);
    gemm_fb<1><<<dim3(N / FBN, M / FBM), dim3(256), 0, stream>>>(nullptr, Wb, A, nullptr, nullptr, C, M, N, K);
  } else {
    gemm_fb<2><<<dim3(N / FBN, M / FBM), dim3(256), 0, stream>>>(nullptr, nullptr, A, Wq, S, C, M, N, K);
  }
}